// Round 1
// baseline (155.358 us; speedup 1.0000x reference)
//
#include <hip/hip_runtime.h>
#include <math.h>

#define NB 32    // batch
#define NS 128   // steps
#define NI 256   // in_dim
#define NC 128   // num capsules
#define ND 64    // dim capsule

// ---------------------------------------------------------------------------
// K1: M[b,s,d] = sum_i u[b,s,i] * W[i,d];  U[b,s] = sum_i u[b,s,i]
// grid = NB*NS/4 blocks, 256 threads (4 rows x 64 d)
// ---------------------------------------------------------------------------
__global__ __launch_bounds__(256) void k_proj(const float* __restrict__ u,
                                              const float* __restrict__ W,
                                              float* __restrict__ Mg,
                                              float* __restrict__ Ug) {
    int row = blockIdx.x * 4 + (threadIdx.x >> 6);   // b*NS + s
    int d   = threadIdx.x & 63;
    const float* ur = u + row * NI;
    float acc = 0.f, rs = 0.f;
#pragma unroll 4
    for (int i = 0; i < NI; ++i) {
        float v = ur[i];
        acc = fmaf(v, W[i * ND + d], acc);
        rs += v;
    }
    Mg[row * ND + d] = acc;
    if (d == 0) Ug[row] = rs;
}

// ---------------------------------------------------------------------------
// Softmax over capsule axis n for each (b,s) row; multiplies by mask.
// b-logits laid out [b][s][n] (contiguous n) -> coalesced.
// grid = NB*NS blocks, 128 threads
// ---------------------------------------------------------------------------
__global__ __launch_bounds__(128) void k_softmax(const float* __restrict__ bl,
                                                 const float* __restrict__ mask,
                                                 float* __restrict__ c) {
    int row = blockIdx.x;          // b*NS + s
    int n   = threadIdx.x;         // 0..127
    float v = bl[row * NC + n];

    float mx = v;
#pragma unroll
    for (int o = 32; o > 0; o >>= 1) mx = fmaxf(mx, __shfl_xor(mx, o));
    __shared__ float wmax[2];
    if ((n & 63) == 0) wmax[n >> 6] = mx;
    __syncthreads();
    mx = fmaxf(wmax[0], wmax[1]);

    float e = expf(v - mx);
    float sm = e;
#pragma unroll
    for (int o = 32; o > 0; o >>= 1) sm += __shfl_xor(sm, o);
    __shared__ float wsum[2];
    if ((n & 63) == 0) wsum[n >> 6] = sm;
    __syncthreads();
    float tot = wsum[0] + wsum[1];

    c[row * NC + n] = e / tot * mask[row];
}

// ---------------------------------------------------------------------------
// One routing step for one (b,n) pair per block.
//   uh[s][d] = M[b,s,d] + pe1[n,d]*U[b,s] + pe2[s, n*64+d]   (built in LDS)
//   out_pre[d] = sum_s c[b,n,s] * uh[s][d];  out = squash(out_pre)
//   if !last: bout[b][s][n] = sum_d out[d] * uh[s][d]
//   if last:  outg[b*NC+n][d] = out[d]
// grid = NB*NC blocks, 256 threads. LDS ~36KB -> 4 blocks/CU.
// ---------------------------------------------------------------------------
__global__ __launch_bounds__(256) void k_route(const float* __restrict__ Mg,
                                               const float* __restrict__ Ug,
                                               const float* __restrict__ mask,
                                               const float* __restrict__ cg,
                                               float* __restrict__ bout,
                                               float* __restrict__ outg,
                                               int first, int last) {
    int bn = blockIdx.x;
    int b  = bn >> 7;
    int n  = bn & 127;
    int t  = threadIdx.x;

    __shared__ float uh[NS][ND + 1];   // +1 pad: both access patterns <=2-way banks
    __shared__ float pe1v[ND];
    __shared__ float if2[ND];
    __shared__ float Us[NS];
    __shared__ float cv[NS];
    __shared__ float red[4][ND];
    __shared__ float outv[ND];

    const float L4 = 9.210340371976184f;  // ln(10000)
    if (t < ND) {
        int k1 = t >> 1;
        float ang = (float)n * expf(-L4 * (float)k1 * (1.f / 32.f));
        float s1, c1;
        __sincosf(ang, &s1, &c1);
        pe1v[t] = (t & 1) ? c1 : s1;
        int k2 = n * 32 + k1;              // (n*64+d) >> 1
        if2[t] = expf(-L4 * (float)k2 * (1.f / 4096.f));
    }
    if (t < NS) {
        Us[t] = Ug[b * NS + t];
        cv[t] = first ? (mask[b * NS + t] * (1.f / 128.f))
                      : cg[(b * NS + t) * NC + n];
    }
    __syncthreads();

    // ---- build uh tile (coalesced M reads: Mb[idx], idx = s*64+d) ----
    const float* Mb = Mg + b * NS * ND;
#pragma unroll 4
    for (int e = 0; e < 32; ++e) {
        int idx = e * 256 + t;
        int s = idx >> 6;
        int d = idx & 63;
        float sv, cvv;
        __sincosf((float)s * if2[d], &sv, &cvv);
        float pe2 = (d & 1) ? cvv : sv;
        uh[s][d] = Mb[idx] + pe1v[d] * Us[s] + pe2;
    }
    __syncthreads();

    // ---- out_pre[d] = sum_s cv[s]*uh[s][d] : 64 d-lanes x 4 s-partials ----
    {
        int d = t & 63, sp = t >> 6;
        float acc = 0.f;
#pragma unroll 8
        for (int s = sp; s < NS; s += 4) acc = fmaf(cv[s], uh[s][d], acc);
        red[sp][d] = acc;
    }
    __syncthreads();

    // ---- squash on wave 0 ----
    if (t < ND) {
        float op = red[0][t] + red[1][t] + red[2][t] + red[3][t];
        float ss = op * op;
#pragma unroll
        for (int o = 32; o > 0; o >>= 1) ss += __shfl_xor(ss, o);
        float scale = ss / (1.f + ss) * rsqrtf(ss + 1e-7f);
        float od = scale * op;
        outv[t] = od;
        if (last) outg[bn * ND + t] = od;
    }
    __syncthreads();

    // ---- new logits: bout[b][s][n] = sum_d outv[d]*uh[s][d] ----
    if (!last && t < NS) {
        float a2 = 0.f;
#pragma unroll 8
        for (int dd = 0; dd < ND; ++dd) a2 = fmaf(outv[dd], uh[t][dd], a2);
        bout[(b * NS + t) * NC + n] = a2;
    }
}

// ---------------------------------------------------------------------------
extern "C" void kernel_launch(void* const* d_in, const int* in_sizes, int n_in,
                              void* d_out, int out_size, void* d_ws, size_t ws_size,
                              hipStream_t stream) {
    const float* u    = (const float*)d_in[0];  // (32,128,256)
    const float* mask = (const float*)d_in[1];  // (32,128)
    const float* W    = (const float*)d_in[2];  // (1,256,64)
    float* out = (float*)d_out;                 // (32,128,64)

    float* ws = (float*)d_ws;
    float* Mg = ws;                    // NB*NS*ND = 262144 floats
    float* Ug = Mg + NB * NS * ND;     // NB*NS    = 4096
    float* bl = Ug + NB * NS;          // NB*NS*NC = 524288  (logits, [b][s][n])
    float* cb = bl + NB * NS * NC;     // NB*NS*NC = 524288  (coupling coeffs)

    k_proj<<<NB * NS / 4, 256, 0, stream>>>(u, W, Mg, Ug);

    // routing iter 0 (uniform c = mask/128), produces logits bl
    k_route<<<NB * NC, 256, 0, stream>>>(Mg, Ug, mask, cb, bl, out, 1, 0);
    k_softmax<<<NB * NS, 128, 0, stream>>>(bl, mask, cb);
    // routing iter 1
    k_route<<<NB * NC, 256, 0, stream>>>(Mg, Ug, mask, cb, bl, out, 0, 0);
    k_softmax<<<NB * NS, 128, 0, stream>>>(bl, mask, cb);
    // routing iter 2 (final) -> writes d_out
    k_route<<<NB * NC, 256, 0, stream>>>(Mg, Ug, mask, cb, bl, out, 0, 1);
}